// Round 2
// baseline (63.482 us; speedup 1.0000x reference)
//
#include <hip/hip_runtime.h>

// desc[b,f,i,:] = sum_j s(|ri-rj|) * (ri-rj), s = smooth cosine cutoff.
// B=4,F=4,N=1024 -> 16 frames, 16.8M pairs, pure compute-bound.
//
// Layout: 512 blocks = 16 frames x 32 i-blocks (32 i each).
// Block = 256 threads: i_group = tid&7 (8 groups x IPT=4 i in registers),
// jc = tid>>3 (32 chunks x 32 j). One ds_read_b128 of cj feeds 4 pair
// updates (4x fewer LDS reads, 4 independent dep chains per read).
//
// LDS: chunks of 32 j stored at stride 33 float4 -> read addr = 33*jc + t
// with t linear => one base reg + immediate offsets, zero inner-loop addr
// math. (33*jc+t)%8 = (jc+t)%8 distinct across the 8 jc's of a wave =>
// conflict-free.

#define NA     1024
#define IPB    32   // i per block
#define IPT    4    // i per thread (registers)
#define JLEN   32   // j per chunk
#define STRIDE 33   // padded chunk stride (float4 units)

__global__ __launch_bounds__(256) void desc_kernel(const float* __restrict__ coord,
                                                   float* __restrict__ out) {
    __shared__ float4 s_c[32 * STRIDE];      // 1056 * 16B = 16.9 KB
    __shared__ float  s_red[4][8][IPT][3];   // per-wave partials

    const int tid   = threadIdx.x;
    const int blk   = blockIdx.x;
    const int frame = blk >> 5;   // 32 i-blocks per frame
    const int ibk   = blk & 31;
    const int ig    = tid & 7;    // i-group
    const int jc    = tid >> 3;   // j-chunk 0..31

    const float* gf = coord + frame * (NA * 3);

    // stage frame coords -> stride-33 padded float4 LDS
    for (int a = tid; a < NA; a += 256) {
        const int slot = (a >> 5) * STRIDE + (a & 31);
        s_c[slot] = make_float4(gf[3 * a], gf[3 * a + 1], gf[3 * a + 2], 0.0f);
    }
    __syncthreads();

    float cx[IPT], cy[IPT], cz[IPT];
    float ax[IPT], ay[IPT], az[IPT];
#pragma unroll
    for (int k = 0; k < IPT; ++k) {
        const float4 c = s_c[ibk * STRIDE + ig * IPT + k];
        cx[k] = c.x; cy[k] = c.y; cz[k] = c.z;
        ax[k] = 0.0f; ay[k] = 0.0f; az[k] = 0.0f;
    }

    const float INV11 = 1.0f / 11.0f;   // rev = (r - 0.5) / (2 * 5.5)
    const float OFF   = -0.5f / 11.0f;
    const float4* cb = &s_c[jc * STRIDE];   // base computed once

#pragma unroll 4
    for (int t = 0; t < JLEN; ++t) {
        const float4 cj = cb[t];            // ds_read_b128, immediate offset
#pragma unroll
        for (int k = 0; k < IPT; ++k) {
            const float dx = cx[k] - cj.x;
            const float dy = cy[k] - cj.y;
            const float dz = cz[k] - cj.z;
            const float d2 = fmaf(dx, dx, fmaf(dy, dy, fmaf(dz, dz, 1e-10f)));
            const float r  = __builtin_amdgcn_sqrtf(d2);
            const float rev = __builtin_amdgcn_fmed3f(fmaf(r, INV11, OFF), 0.0f, 0.5f);
            const float s  = fmaf(0.5f, __builtin_amdgcn_cosf(rev), 0.5f);
            ax[k] = fmaf(s, dx, ax[k]);
            ay[k] = fmaf(s, dy, ay[k]);
            az[k] = fmaf(s, dz, az[k]);
        }
    }

    // reduce across the 8 jc's inside each wave (tid bits 3,4,5)
#pragma unroll
    for (int k = 0; k < IPT; ++k) {
        ax[k] += __shfl_xor(ax[k], 8, 64);  ax[k] += __shfl_xor(ax[k], 16, 64);  ax[k] += __shfl_xor(ax[k], 32, 64);
        ay[k] += __shfl_xor(ay[k], 8, 64);  ay[k] += __shfl_xor(ay[k], 16, 64);  ay[k] += __shfl_xor(ay[k], 32, 64);
        az[k] += __shfl_xor(az[k], 8, 64);  az[k] += __shfl_xor(az[k], 16, 64);  az[k] += __shfl_xor(az[k], 32, 64);
    }

    const int wave = tid >> 6;
    if ((tid & 56) == 0) {                  // one leader lane per i-group per wave
#pragma unroll
        for (int k = 0; k < IPT; ++k) {
            s_red[wave][ig][k][0] = ax[k];
            s_red[wave][ig][k][1] = ay[k];
            s_red[wave][ig][k][2] = az[k];
        }
    }
    __syncthreads();

    // final reduce across 4 waves; 96 threads write 32 atoms x 3 comps
    if (tid < IPB * 3) {
        const int il   = tid / 3;
        const int comp = tid - il * 3;
        const int g    = il >> 2;
        const int k    = il & 3;
        const float v = s_red[0][g][k][comp] + s_red[1][g][k][comp] +
                        s_red[2][g][k][comp] + s_red[3][g][k][comp];
        out[frame * (NA * 3) + (ibk * IPB + il) * 3 + comp] = v;
    }
}

extern "C" void kernel_launch(void* const* d_in, const int* in_sizes, int n_in,
                              void* d_out, int out_size, void* d_ws, size_t ws_size,
                              hipStream_t stream) {
    const float* coord = (const float*)d_in[0];
    float*       out   = (float*)d_out;
    (void)d_ws; (void)ws_size; (void)n_in; (void)out_size;

    const int frames = in_sizes[0] / (NA * 3);   // B*F = 16
    const int blocks = frames * (NA / IPB);      // 512

    hipLaunchKernelGGL(desc_kernel, dim3(blocks), dim3(256), 0, stream, coord, out);
}